// Round 7
// baseline (234.251 us; speedup 1.0000x reference)
//
#include <hip/hip_runtime.h>
#include <hip/hip_bf16.h>

#define BDIM 256
#define NROW 64      // S = O = 64
#define DDIM 512
#define BK 64        // fp32 cols per chunk
#define NCHUNK 8     // 512/64
#define FDIM 32
#define BBATCH 32
#define NBLK (FDIM * BBATCH)

typedef short bf16x8 __attribute__((ext_vector_type(8)));
typedef float f32x4 __attribute__((ext_vector_type(4)));

__device__ __forceinline__ unsigned short f2bf(float f) {
    unsigned int u = __float_as_uint(f);
    u += 0x7FFFu + ((u >> 16) & 1u);   // round-to-nearest-even
    return (unsigned short)(u >> 16);
}

__device__ __forceinline__ float sumsq4(const float4& v) {
    return v.x*v.x + v.y*v.y + v.z*v.z + v.w*v.w;
}

// async global->LDS, 16B per lane; LDS dest = wave-uniform base + lane*16 (HW scatter)
__device__ __forceinline__ void gload_lds16(const float* g, float* l) {
    __builtin_amdgcn_global_load_lds(
        (const __attribute__((address_space(1))) void*)g,
        (__attribute__((address_space(3))) void*)l, 16, 0, 0);
}

#define BARRIER() do { asm volatile("" ::: "memory"); \
                       __builtin_amdgcn_s_barrier();  \
                       asm volatile("" ::: "memory"); } while (0)

// stage one BK=64 fp32 chunk of A and B into buf (linear LDS, row stride 256B).
// global SOURCE is pre-swizzled (off ^= (row&7)<<4) so that swizzled ds_reads
// later see their data; LDS write itself stays linear (rule: both-sides-or-neither).
__device__ __forceinline__ void stage_chunk(const float* __restrict__ gA,
                                            const float* __restrict__ gB,
                                            float* bufA, float* bufB,
                                            int c, int w, int lane) {
    const int sub  = lane >> 4;          // row within 4-row group
    const int slot = lane & 15;          // 16B slot within 256B row
#pragma unroll
    for (int i = 0; i < 4; ++i) {
        const int rg   = w * 16 + i * 4;            // wave-uniform row-group base
        const int row  = rg + sub;                  // this lane's row
        const int goff = (slot * 16) ^ ((row & 7) << 4);   // pre-swizzled byte off
        const float* ga = gA + (size_t)row * DDIM + c * BK + (goff >> 2);
        const float* gb = gB + (size_t)row * DDIM + c * BK + (goff >> 2);
        gload_lds16(ga, bufA + rg * BK);            // dest: uniform base + lane*16
        gload_lds16(gb, bufB + rg * BK);
    }
}

// read 8 fp32 (cols kb..kb+8) of `row` from swizzled LDS, accumulate sumsq,
// return bf16x8 MFMA fragment
__device__ __forceinline__ bf16x8 read_frag(const float* buf, int row, int kb, float& ssq) {
    const int swz  = (row & 7) << 4;
    const int boff = kb * 4;
    const char* base = (const char*)buf + (row << 8);          // row*256B
    const float4 lo = *(const float4*)(base + (boff ^ swz));
    const float4 hi = *(const float4*)(base + ((boff + 16) ^ swz));
    ssq += sumsq4(lo) + sumsq4(hi);
    bf16x8 r;
    r[0] = (short)f2bf(lo.x); r[1] = (short)f2bf(lo.y);
    r[2] = (short)f2bf(lo.z); r[3] = (short)f2bf(lo.w);
    r[4] = (short)f2bf(hi.x); r[5] = (short)f2bf(hi.y);
    r[6] = (short)f2bf(hi.z); r[7] = (short)f2bf(hi.w);
    return r;
}

__global__ __launch_bounds__(BDIM) void pwl_main(
        const float* __restrict__ pred, const float* __restrict__ slots,
        const int* __restrict__ labels, const unsigned char* __restrict__ vmask,
        float* __restrict__ partial) {
    // 4 fp32 chunk buffers: A0,A1,B0,B1 — 64 KB total; simbuf overlays the front
    __shared__ __align__(1024) float smemf[4][NROW][BK];
    float (*simbuf)[65] = reinterpret_cast<float(*)[65]>(&smemf[0][0][0]);  // 16640B

    __shared__ float rnA[NROW], rnB[NROW];
    __shared__ float wsum_f[4], wsum_c[4];

    const int t   = threadIdx.x;
    const int bid = blockIdx.x;          // bid = b*F + f  (matches [B,F,...] layout)
    const int b   = bid >> 5;
    const int f   = bid & 31;
    const float* gA = slots + (size_t)bid * NROW * DDIM;
    const float* gB = pred  + (size_t)bid * NROW * DDIM;

    const int lane = t & 63;
    const int w    = t >> 6;
    const int wr   = (w >> 1) * 32;      // s-quadrant base
    const int wc   = (w & 1) * 32;       // o-quadrant base
    const int lr   = lane & 15;
    const int lk   = (lane >> 4) * 8;

    f32x4 acc00 = {0,0,0,0}, acc01 = {0,0,0,0}, acc10 = {0,0,0,0}, acc11 = {0,0,0,0};
    float sq0 = 0.f, sq1 = 0.f, sq2 = 0.f, sq3 = 0.f;

    // prologue: chunks 0 and 1 in flight (16 gload_lds outstanding per lane)
    stage_chunk(gA, gB, &smemf[0][0][0], &smemf[2][0][0], 0, w, lane);
    stage_chunk(gA, gB, &smemf[1][0][0], &smemf[3][0][0], 1, w, lane);

#pragma unroll
    for (int c = 0; c < NCHUNK; ++c) {
        const int p = c & 1;
        // chunk c ready when only chunk c+1's 8 loads remain outstanding
        if (c == NCHUNK - 1) asm volatile("s_waitcnt vmcnt(0)" ::: "memory");
        else                 asm volatile("s_waitcnt vmcnt(8)" ::: "memory");
        BARRIER();                        // all waves' chunk-c data landed

        const float* bA = &smemf[p][0][0];
        const float* bB = &smemf[2 + p][0][0];
#pragma unroll
        for (int kk = 0; kk < 2; ++kk) {
            const int kb = kk * 32 + lk;
            const bf16x8 A0 = read_frag(bA, wr      + lr, kb, sq0);
            const bf16x8 A1 = read_frag(bA, wr + 16 + lr, kb, sq1);
            const bf16x8 B0 = read_frag(bB, wc      + lr, kb, sq2);
            const bf16x8 B1 = read_frag(bB, wc + 16 + lr, kb, sq3);
            acc00 = __builtin_amdgcn_mfma_f32_16x16x32_bf16(A0, B0, acc00, 0, 0, 0);
            acc01 = __builtin_amdgcn_mfma_f32_16x16x32_bf16(A0, B1, acc01, 0, 0, 0);
            acc10 = __builtin_amdgcn_mfma_f32_16x16x32_bf16(A1, B0, acc10, 0, 0, 0);
            acc11 = __builtin_amdgcn_mfma_f32_16x16x32_bf16(A1, B1, acc11, 0, 0, 0);
        }
        BARRIER();                        // everyone done reading buf[p]
        if (c + 2 < NCHUNK)               // refill buf[p]; lands by wait at c+2
            stage_chunk(gA, gB, &smemf[p][0][0], &smemf[2 + p][0][0], c + 2, w, lane);
    }

    // full-row sumsq: lanes {lr, lr+16, lr+32, lr+48} hold disjoint col-slices
    sq0 += __shfl_xor(sq0, 16); sq0 += __shfl_xor(sq0, 32);
    sq1 += __shfl_xor(sq1, 16); sq1 += __shfl_xor(sq1, 32);
    sq2 += __shfl_xor(sq2, 16); sq2 += __shfl_xor(sq2, 32);
    sq3 += __shfl_xor(sq3, 16); sq3 += __shfl_xor(sq3, 32);
    if (lane < 16) {
        if ((w & 1) == 0) {              // w0: A rows 0-31, w2: A rows 32-63
            rnA[wr      + lr] = 1.f / fmaxf(sqrtf(sq0), 1e-12f);
            rnA[wr + 16 + lr] = 1.f / fmaxf(sqrtf(sq1), 1e-12f);
        }
        if (w < 2) {                     // w0: B rows 0-31, w1: B rows 32-63
            rnB[wc      + lr] = 1.f / fmaxf(sqrtf(sq2), 1e-12f);
            rnB[wc + 16 + lr] = 1.f / fmaxf(sqrtf(sq3), 1e-12f);
        }
    }
    __syncthreads();   // rn ready; all LDS chunk reads done -> simbuf overlay safe

    // normalize accumulators, write sim to LDS (C/D layout: col=lane&15, row=(lane>>4)*4+j)
    {
        const int r0 = wr + (lane >> 4) * 4;
        const int c0 = wc + lr;
#pragma unroll
        for (int j = 0; j < 4; ++j) {
            simbuf[r0 + j     ][c0     ] = acc00[j] * rnA[r0 + j     ] * rnB[c0     ];
            simbuf[r0 + j     ][c0 + 16] = acc01[j] * rnA[r0 + j     ] * rnB[c0 + 16];
            simbuf[r0 + 16 + j][c0     ] = acc10[j] * rnA[r0 + 16 + j] * rnB[c0     ];
            simbuf[r0 + 16 + j][c0 + 16] = acc11[j] * rnA[r0 + 16 + j] * rnB[c0 + 16];
        }
    }
    __syncthreads();

    // softmax over objects + focal at label; 4 lanes per s-row
    float contrib = 0.f, ccnt = 0.f;
    {
        const int s = t >> 2;
        const int q = t & 3;
        float v[16];
        float mx = -1e30f;
#pragma unroll
        for (int jj = 0; jj < 16; ++jj) {
            v[jj] = simbuf[s][q * 16 + jj];
            mx = fmaxf(mx, v[jj]);
        }
        mx = fmaxf(mx, __shfl_xor(mx, 1));
        mx = fmaxf(mx, __shfl_xor(mx, 2));
        float se = 0.f;
#pragma unroll
        for (int jj = 0; jj < 16; ++jj) se += __expf(v[jj] - mx);
        se += __shfl_xor(se, 1);
        se += __shfl_xor(se, 2);
        if (q == 0) {
            const int lab = labels[(f * BBATCH + b) * NROW + s];
            if (lab >= 0) {
                const float simt  = simbuf[s][lab];
                const float pt    = __expf(simt - mx) / se;
                const float u     = 1.f - pt + 1e-12f;
                const float focal = u * u * __logf(pt + 1e-12f);
                contrib = focal;
                ccnt    = 1.f;
            }
        }
    }
    // wave-level reduce (no LDS/global atomics anywhere)
#pragma unroll
    for (int m = 1; m <= 32; m <<= 1) {
        contrib += __shfl_xor(contrib, m);
        ccnt    += __shfl_xor(ccnt, m);
    }
    if (lane == 0) { wsum_f[w] = contrib; wsum_c[w] = ccnt; }
    __syncthreads();
    if (t == 0) {
        const float rf  = wsum_f[0] + wsum_f[1] + wsum_f[2] + wsum_f[3];
        const float ri  = wsum_c[0] + wsum_c[1] + wsum_c[2] + wsum_c[3];
        const float cnt = fmaxf(ri, 1.f);
        const float nll = -rf / cnt;
        const float vv  = vmask[f * BBATCH + b] ? 1.f : 0.f;
        partial[bid] = 100.f * nll * vv;   // distinct address per block: no contention
    }
}

__global__ __launch_bounds__(BDIM) void pwl_finalize(
        const unsigned char* __restrict__ vmask, const float* __restrict__ partial,
        float* __restrict__ out) {
    __shared__ float sf[4], sv[4];
    const int t = threadIdx.x;
    const float4 p = reinterpret_cast<const float4*>(partial)[t];      // 256*4 = 1024
    float s = p.x + p.y + p.z + p.w;
    const uchar4 mv = reinterpret_cast<const uchar4*>(vmask)[t];       // 256*4 = 1024
    float vs = (mv.x ? 1.f : 0.f) + (mv.y ? 1.f : 0.f) + (mv.z ? 1.f : 0.f) + (mv.w ? 1.f : 0.f);
#pragma unroll
    for (int m = 1; m <= 32; m <<= 1) { s += __shfl_xor(s, m); vs += __shfl_xor(vs, m); }
    if ((t & 63) == 0) { sf[t >> 6] = s; sv[t >> 6] = vs; }
    __syncthreads();
    if (t == 0) {
        const float loss = sf[0] + sf[1] + sf[2] + sf[3];
        const float sums = sv[0] + sv[1] + sv[2] + sv[3];
        out[0] = (sums > 0.f) ? loss / (32.0f * sums) : loss;
    }
}

extern "C" void kernel_launch(void* const* d_in, const int* in_sizes, int n_in,
                              void* d_out, int out_size, void* d_ws, size_t ws_size,
                              hipStream_t stream) {
    const float* pred          = (const float*)d_in[0];
    const float* slots         = (const float*)d_in[1];
    const int* labels          = (const int*)d_in[2];
    const unsigned char* vmask = (const unsigned char*)d_in[3];
    float* out     = (float*)d_out;
    float* partial = (float*)d_ws;   // 1024 floats; every slot written every call

    pwl_main<<<dim3(NBLK), dim3(BDIM), 0, stream>>>(pred, slots, labels, vmask, partial);
    pwl_finalize<<<dim3(1), dim3(BDIM), 0, stream>>>(vmask, partial, out);
}

// Round 8
// 49.540 us; speedup vs baseline: 4.7286x; 4.7286x over previous
//
#include <hip/hip_runtime.h>
#include <hip/hip_bf16.h>

#define BDIM 256
#define NROW 64      // S = O = 64
#define DDIM 512
#define BK 64        // fp32 cols per chunk
#define NCHUNK 8     // 512/64
#define LDK 72       // shorts: 64 + 8 pad -> 144B row stride (16B-aligned, dword-stride 36)
#define FDIM 32
#define BBATCH 32
#define NBLK (FDIM * BBATCH)

typedef short bf16x8 __attribute__((ext_vector_type(8)));
typedef float f32x4 __attribute__((ext_vector_type(4)));

__device__ __forceinline__ unsigned short f2bf(float f) {
    unsigned int u = __float_as_uint(f);
    u += 0x7FFFu + ((u >> 16) & 1u);   // round-to-nearest-even
    return (unsigned short)(u >> 16);
}

__device__ __forceinline__ ushort4 pack4(const float4& v) {
    ushort4 r;
    r.x = f2bf(v.x); r.y = f2bf(v.y); r.z = f2bf(v.z); r.w = f2bf(v.w);
    return r;
}

__device__ __forceinline__ float sumsq4(const float4& v) {
    return v.x*v.x + v.y*v.y + v.z*v.z + v.w*v.w;
}

__global__ __launch_bounds__(BDIM, 8) void pwl_main(
        const float* __restrict__ pred, const float* __restrict__ slots,
        const int* __restrict__ labels, const unsigned char* __restrict__ vmask,
        float* __restrict__ partial) {
    // single-buffered bf16 staging (~19KB total -> 8 blocks/CU);
    // simbuf overlays lA/lB (only written after the post-MFMA barrier)
    __shared__ __align__(16) unsigned char smem[2 * NROW * LDK * sizeof(unsigned short)];
    unsigned short (*lA)[LDK] = reinterpret_cast<unsigned short(*)[LDK]>(smem);
    unsigned short (*lB)[LDK] = reinterpret_cast<unsigned short(*)[LDK]>(
        smem + NROW * LDK * sizeof(unsigned short));
    float (*simbuf)[65] = reinterpret_cast<float(*)[65]>(smem);  // 16640 <= 18432

    __shared__ float rnA[NROW], rnB[NROW];
    __shared__ float wsum_f[4], wsum_c[4];

    const int t   = threadIdx.x;
    const int bid = blockIdx.x;          // bid = b*F + f  (matches [B,F,...] layout)
    const int b   = bid >> 5;
    const int f   = bid & 31;
    const float* gA = slots + (size_t)bid * NROW * DDIM;
    const float* gB = pred  + (size_t)bid * NROW * DDIM;

    const int lane = t & 63;
    const int w    = t >> 6;
    const int wr   = (w >> 1) * 32;      // s-quadrant base
    const int wc   = (w & 1) * 32;       // o-quadrant base
    const int lr   = lane & 15;
    const int lk   = (lane >> 4) * 8;
    const int tr   = t >> 4;             // staging row-class (0..15)
    const int ts   = t & 15;             // staging slot (float4 index in 64-col chunk)

    f32x4 acc00 = {0,0,0,0}, acc01 = {0,0,0,0}, acc10 = {0,0,0,0}, acc11 = {0,0,0,0};
    float sqa[4], sqb[4];
#pragma unroll
    for (int i = 0; i < 4; ++i) { sqa[i] = 0.f; sqb[i] = 0.f; }

    for (int c = 0; c < NCHUNK; ++c) {
        if (c) __syncthreads();          // prev chunk's MFMA reads done before overwrite
        const int cb = c * BK;
        // load + sumsq + cvt + LDS write (loads consumed in-place: no spillable state)
#pragma unroll
        for (int i = 0; i < 4; ++i) {
            const int row = i * 16 + tr;
            const float4 va = *reinterpret_cast<const float4*>(gA + (size_t)row * DDIM + cb + ts * 4);
            const float4 vb = *reinterpret_cast<const float4*>(gB + (size_t)row * DDIM + cb + ts * 4);
            sqa[i] += sumsq4(va);
            sqb[i] += sumsq4(vb);
            *reinterpret_cast<ushort4*>(&lA[row][ts * 4]) = pack4(va);
            *reinterpret_cast<ushort4*>(&lB[row][ts * 4]) = pack4(vb);
        }
        __syncthreads();
#pragma unroll
        for (int kk = 0; kk < 2; ++kk) {
            const int kb = kk * 32 + lk;
            const bf16x8 a0 = *reinterpret_cast<const bf16x8*>(&lA[wr      + lr][kb]);
            const bf16x8 a1 = *reinterpret_cast<const bf16x8*>(&lA[wr + 16 + lr][kb]);
            const bf16x8 b0 = *reinterpret_cast<const bf16x8*>(&lB[wc      + lr][kb]);
            const bf16x8 b1 = *reinterpret_cast<const bf16x8*>(&lB[wc + 16 + lr][kb]);
            acc00 = __builtin_amdgcn_mfma_f32_16x16x32_bf16(a0, b0, acc00, 0, 0, 0);
            acc01 = __builtin_amdgcn_mfma_f32_16x16x32_bf16(a0, b1, acc01, 0, 0, 0);
            acc10 = __builtin_amdgcn_mfma_f32_16x16x32_bf16(a1, b0, acc10, 0, 0, 0);
            acc11 = __builtin_amdgcn_mfma_f32_16x16x32_bf16(a1, b1, acc11, 0, 0, 0);
        }
    }

    // row sumsq: row r = i*16+tr partials live in 16 consecutive lanes (ts) of one wave
#pragma unroll
    for (int i = 0; i < 4; ++i) {
        float x = sqa[i], y = sqb[i];
#pragma unroll
        for (int m = 1; m <= 8; m <<= 1) { x += __shfl_xor(x, m); y += __shfl_xor(y, m); }
        if (ts == 0) {
            const int row = i * 16 + tr;
            rnA[row] = 1.f / fmaxf(sqrtf(x), 1e-12f);
            rnB[row] = 1.f / fmaxf(sqrtf(y), 1e-12f);
        }
    }
    __syncthreads();   // all MFMA done -> simbuf (overlaying lA/lB) safe to write

    // normalize accumulators, write sim to LDS (C/D layout: col=lane&15, row=(lane>>4)*4+j)
    {
        const int r0 = wr + (lane >> 4) * 4;
        const int c0 = wc + lr;
#pragma unroll
        for (int j = 0; j < 4; ++j) {
            simbuf[r0 + j     ][c0     ] = acc00[j] * rnA[r0 + j     ] * rnB[c0     ];
            simbuf[r0 + j     ][c0 + 16] = acc01[j] * rnA[r0 + j     ] * rnB[c0 + 16];
            simbuf[r0 + 16 + j][c0     ] = acc10[j] * rnA[r0 + 16 + j] * rnB[c0     ];
            simbuf[r0 + 16 + j][c0 + 16] = acc11[j] * rnA[r0 + 16 + j] * rnB[c0 + 16];
        }
    }
    __syncthreads();

    // softmax over objects + focal at label; 4 lanes per s-row
    float contrib = 0.f, ccnt = 0.f;
    {
        const int s = t >> 2;
        const int q = t & 3;
        float v[16];
        float mx = -1e30f;
#pragma unroll
        for (int jj = 0; jj < 16; ++jj) {
            v[jj] = simbuf[s][q * 16 + jj];
            mx = fmaxf(mx, v[jj]);
        }
        mx = fmaxf(mx, __shfl_xor(mx, 1));
        mx = fmaxf(mx, __shfl_xor(mx, 2));
        float se = 0.f;
#pragma unroll
        for (int jj = 0; jj < 16; ++jj) se += __expf(v[jj] - mx);
        se += __shfl_xor(se, 1);
        se += __shfl_xor(se, 2);
        if (q == 0) {
            const int lab = labels[(f * BBATCH + b) * NROW + s];
            if (lab >= 0) {
                const float simt  = simbuf[s][lab];
                const float pt    = __expf(simt - mx) / se;
                const float u     = 1.f - pt + 1e-12f;
                const float focal = u * u * __logf(pt + 1e-12f);
                contrib = focal;
                ccnt    = 1.f;
            }
        }
    }
    // wave-level reduce (no LDS/global atomics anywhere)
#pragma unroll
    for (int m = 1; m <= 32; m <<= 1) {
        contrib += __shfl_xor(contrib, m);
        ccnt    += __shfl_xor(ccnt, m);
    }
    if (lane == 0) { wsum_f[w] = contrib; wsum_c[w] = ccnt; }
    __syncthreads();
    if (t == 0) {
        const float rf  = wsum_f[0] + wsum_f[1] + wsum_f[2] + wsum_f[3];
        const float ri  = wsum_c[0] + wsum_c[1] + wsum_c[2] + wsum_c[3];
        const float cnt = fmaxf(ri, 1.f);
        const float nll = -rf / cnt;
        const float vv  = vmask[f * BBATCH + b] ? 1.f : 0.f;
        partial[bid] = 100.f * nll * vv;   // distinct address per block: no contention
    }
}

__global__ __launch_bounds__(BDIM) void pwl_finalize(
        const unsigned char* __restrict__ vmask, const float* __restrict__ partial,
        float* __restrict__ out) {
    __shared__ float sf[4], sv[4];
    const int t = threadIdx.x;
    const float4 p = reinterpret_cast<const float4*>(partial)[t];      // 256*4 = 1024
    float s = p.x + p.y + p.z + p.w;
    const uchar4 mv = reinterpret_cast<const uchar4*>(vmask)[t];       // 256*4 = 1024
    float vs = (mv.x ? 1.f : 0.f) + (mv.y ? 1.f : 0.f) + (mv.z ? 1.f : 0.f) + (mv.w ? 1.f : 0.f);
#pragma unroll
    for (int m = 1; m <= 32; m <<= 1) { s += __shfl_xor(s, m); vs += __shfl_xor(vs, m); }
    if ((t & 63) == 0) { sf[t >> 6] = s; sv[t >> 6] = vs; }
    __syncthreads();
    if (t == 0) {
        const float loss = sf[0] + sf[1] + sf[2] + sf[3];
        const float sums = sv[0] + sv[1] + sv[2] + sv[3];
        out[0] = (sums > 0.f) ? loss / (32.0f * sums) : loss;
    }
}

extern "C" void kernel_launch(void* const* d_in, const int* in_sizes, int n_in,
                              void* d_out, int out_size, void* d_ws, size_t ws_size,
                              hipStream_t stream) {
    const float* pred          = (const float*)d_in[0];
    const float* slots         = (const float*)d_in[1];
    const int* labels          = (const int*)d_in[2];
    const unsigned char* vmask = (const unsigned char*)d_in[3];
    float* out     = (float*)d_out;
    float* partial = (float*)d_ws;   // 1024 floats; every slot written every call

    pwl_main<<<dim3(NBLK), dim3(BDIM), 0, stream>>>(pred, slots, labels, vmask, partial);
    pwl_finalize<<<dim3(1), dim3(BDIM), 0, stream>>>(vmask, partial, out);
}